// Round 2
// baseline (5002.396 us; speedup 1.0000x reference)
//
#include <hip/hip_runtime.h>
#include <hip/hip_bf16.h>

typedef __hip_bfloat16 bf16;

constexpr int NN = 307, TT = 12, BB = 32, HH = 64, EE = 10, HEADS = 4, HD = 16, HORIZON = 12;

// ---------------- staged fp32 input offsets (element counts from reference shapes) ----------------
constexpr int S_SRC = 0,       S_EMB = 117888,  S_GW0 = 120958,  S_GB0 = 287358,
              S_UW0 = 288638,  S_UB0 = 371838,  S_GW1 = 372478,  S_GB1 = 700158,
              S_UW1 = 701438,  S_UB1 = 865278,  S_MLW = 865918,  S_MLB = 865982,
              S_WQ  = 866046,  S_BQ  = 870142,  S_WK  = 870206,  S_BK  = 874302,
              S_WV  = 874366,  S_BV  = 878462,  S_WO  = 878526,  S_BO  = 882622,
              S_FW1 = 882686,  S_FB1 = 948222,  S_FW2 = 949246,  S_FB2 = 1014782,
              S_L1G = 1014846, S_L1B = 1014910, S_L2G = 1014974, S_L2B = 1015038,
              S_WS  = 1015102, S_WT  = 1034750, S_CW  = 1054398, S_CB  = 1055166;
constexpr size_t S_TOT = 1055178;

// ---------------- work regions ----------------
constexpr size_t OFF_A     = S_TOT;                              // 307*307
constexpr size_t OFF_WG0n  = OFF_A     + 94249;                  // 307*16640
constexpr size_t OFF_BG0n  = OFF_WG0n  + (size_t)307*16640;      // 307*128
constexpr size_t OFF_WU0n  = OFF_BG0n  + 39296;                  // 307*8320
constexpr size_t OFF_BU0n  = OFF_WU0n  + (size_t)307*8320;       // 307*64
constexpr size_t OFF_WG1n  = OFF_BU0n  + 19648;                  // 307*32768
constexpr size_t OFF_BG1n  = OFF_WG1n  + (size_t)307*32768;      // 307*128
constexpr size_t OFF_WU1n  = OFF_BG1n  + 39296;                  // 307*16384
constexpr size_t OFF_BU1n  = OFF_WU1n  + (size_t)307*16384;      // 307*64
constexpr size_t OFF_OUT0  = OFF_BU1n  + 19648;                  // 32*12*307*64
constexpr size_t OFF_H     = OFF_OUT0  + (size_t)7544832;        // 32*307*64
constexpr size_t OFF_ZH    = OFF_H     + 628736;
constexpr size_t OFF_R     = OFF_ZH    + 628736;
constexpr size_t OFF_AGG_G = OFF_R     + 628736;                 // 32*307*128 max
constexpr size_t OFF_AGG_U = OFF_AGG_G + 1257472;
constexpr size_t OFF_PE    = OFF_AGG_U + 1257472;                // 12*64
constexpr size_t OFF_OLN   = OFF_PE    + 768;                    // 32*307*64
constexpr size_t OFF_O2    = OFF_OLN   + 628736;
constexpr size_t G_TOTAL   = OFF_O2    + 628736;                 // ~37.2M floats ~149 MB

__device__ float g_buf[G_TOTAL];
__device__ int g_flag;   // 1 = inputs are bf16, 0 = inputs are fp32

__device__ __forceinline__ float wave_sum(float v) {
    #pragma unroll
    for (int off = 32; off > 0; off >>= 1) v += __shfl_xor(v, off, 64);
    return v;
}

// ---------------- dtype detection: decode node_emb as bf16; fp32 data yields garbage halves ----------------
__global__ void k_detect(const void* emb_raw) {
    const bf16* p = (const bf16*)emb_raw;
    int lane = threadIdx.x;           // 64 threads, 1 wave
    float v = __bfloat162float(p[lane]);
    bool plaus = (v == v) && (fabsf(v) <= 1e4f) && (v == 0.f || fabsf(v) >= 1e-4f);
    float c = wave_sum(plaus ? 1.f : 0.f);
    if (lane == 0) g_flag = (c >= 52.f) ? 1 : 0;
}

// ---------------- ingest all inputs as fp32 into g_buf ----------------
struct PtrPack { const void* p[32]; };
__device__ const int D_CNT[32] = {117888,3070,166400,1280,83200,640,327680,1280,163840,640,
                                  64,64,4096,64,4096,64,4096,64,4096,64,
                                  65536,1024,65536,64,64,64,64,64,19648,19648,768,12};
__device__ const int D_OFF[32] = {S_SRC,S_EMB,S_GW0,S_GB0,S_UW0,S_UB0,S_GW1,S_GB1,S_UW1,S_UB1,
                                  S_MLW,S_MLB,S_WQ,S_BQ,S_WK,S_BK,S_WV,S_BV,S_WO,S_BO,
                                  S_FW1,S_FB1,S_FW2,S_FB2,S_L1G,S_L1B,S_L2G,S_L2B,S_WS,S_WT,S_CW,S_CB};
__device__ const int D_CHK[33] = {0,461,473,1123,1128,1453,1456,2736,2741,3381,3384,3385,3386,
                                  3402,3403,3419,3420,3436,3437,3453,3454,3710,3714,3970,3971,
                                  3972,3973,3974,3975,4052,4129,4132,4133};

__global__ void k_ingest(PtrPack pk) {
    int bid = blockIdx.x;
    int s = 0;
    while (s < 31 && bid >= D_CHK[s + 1]) s++;
    int i = (bid - D_CHK[s]) * 256 + threadIdx.x;
    if (i >= D_CNT[s]) return;
    float v;
    if (g_flag) v = __bfloat162float(((const bf16*)pk.p[s])[i]);
    else        v = ((const float*)pk.p[s])[i];
    g_buf[(size_t)D_OFF[s] + i] = v;
}

// ---------------- adjacency: A = softmax(relu(emb @ emb^T), axis=1) ----------------
__global__ void k_adj() {
    int n = blockIdx.x;
    int tid = threadIdx.x;            // 512
    __shared__ float en[EE];
    __shared__ float red[512];
    if (tid < EE) en[tid] = g_buf[S_EMB + n * EE + tid];
    __syncthreads();
    bool act = tid < NN;
    float d = 0.f;
    if (act) {
        #pragma unroll
        for (int e = 0; e < EE; e++) d += en[e] * g_buf[S_EMB + tid * EE + e];
        d = fmaxf(d, 0.f);
    }
    red[tid] = act ? d : -1e30f;
    __syncthreads();
    for (int s = 256; s > 0; s >>= 1) { if (tid < s) red[tid] = fmaxf(red[tid], red[tid + s]); __syncthreads(); }
    float mx = red[0];
    __syncthreads();
    float ex = act ? expf(d - mx) : 0.f;
    red[tid] = ex;
    __syncthreads();
    for (int s = 256; s > 0; s >>= 1) { if (tid < s) red[tid] += red[tid + s]; __syncthreads(); }
    float inv = 1.f / red[0];
    if (act) g_buf[OFF_A + (size_t)n * NN + tid] = ex * inv;
}

// ---------------- per-node GRU weights: W[n,j] = sum_e emb[n,e] * w[e,j], all 8 tensors fused ----------------
__device__ const unsigned SEGC[9] = {0u,5108480u,5147776u,7702016u,7721664u,17781440u,17820736u,22850624u,22870272u};
__device__ const int SEGJ[8]      = {16640,128,8320,64,32768,128,16384,64};
__device__ const int SEGS[8]      = {S_GW0,S_GB0,S_UW0,S_UB0,S_GW1,S_GB1,S_UW1,S_UB1};
__device__ const size_t SEGD[8]   = {OFF_WG0n,OFF_BG0n,OFF_WU0n,OFF_BU0n,OFF_WG1n,OFF_BG1n,OFF_WU1n,OFF_BU1n};

__global__ void k_nodew_all() {
    unsigned idx = blockIdx.x * 256u + threadIdx.x;
    if (idx >= 22870272u) return;
    int s = 0;
    while (s < 7 && idx >= SEGC[s + 1]) s++;
    unsigned rem = idx - SEGC[s];
    unsigned J = (unsigned)SEGJ[s];
    unsigned n = rem / J;
    unsigned j = rem - n * J;
    float acc = 0.f;
    const float* eb = g_buf + S_EMB + n * EE;
    const float* w  = g_buf + SEGS[s];
    #pragma unroll
    for (int e = 0; e < EE; e++) acc += eb[e] * w[(size_t)e * J + j];
    g_buf[SEGD[s] + (size_t)n * J + j] = acc;
}

// ---------------- positional embedding ----------------
__global__ void k_pe() {
    int tid = threadIdx.x;            // 768 = 12*64
    int t = tid >> 6, h = tid & 63;
    float ex = (float)(h & ~1) / 64.f;
    float ang = (float)t * powf(10000.f, -ex);
    g_buf[OFF_PE + tid] = (h & 1) ? cosf(ang) : sinf(ang);
}

__global__ void k_zero(size_t off, int cnt) {
    int i = blockIdx.x * 256 + threadIdx.x;
    if (i < cnt) g_buf[off + i] = 0.f;
}

// ---------------- aggregation: agg[b,n,c] = sum_m A[n,m] * concat(x_t, hsrc)[b,m,c] ----------------
template<int CIN>
__global__ void k_agg(int t, size_t hoff, size_t aggoff) {
    constexpr int C = CIN + HH;
    constexpr int NT = 16;
    int b = blockIdx.y;
    int n0 = blockIdx.x * NT;
    int c = threadIdx.x;              // 128
    __shared__ float At[NT][33];
    float acc[NT];
    #pragma unroll
    for (int i = 0; i < NT; i++) acc[i] = 0.f;
    for (int m0 = 0; m0 < NN; m0 += 32) {
        for (int idx = threadIdx.x; idx < NT * 32; idx += 128) {
            int i = idx >> 5, j = idx & 31;
            int nA = n0 + i, mA = m0 + j;
            At[i][j] = (nA < NN && mA < NN) ? g_buf[OFF_A + (size_t)nA * NN + mA] : 0.f;
        }
        __syncthreads();
        int mend = min(32, NN - m0);
        if (c < C) {
            for (int j = 0; j < mend; j++) {
                int m = m0 + j;
                float x;
                if (c < CIN) {
                    if constexpr (CIN == 1) x = g_buf[S_SRC + ((size_t)b * TT + t) * NN + m];
                    else x = g_buf[OFF_OUT0 + (((size_t)b * TT + t) * NN + m) * HH + c];
                } else {
                    x = g_buf[hoff + ((size_t)b * NN + m) * HH + (c - CIN)];
                }
                #pragma unroll
                for (int i = 0; i < NT; i++) acc[i] += At[i][j] * x;
            }
        }
        __syncthreads();
    }
    if (c < C) {
        #pragma unroll
        for (int i = 0; i < NT; i++) {
            int nW = n0 + i;
            if (nW < NN) g_buf[aggoff + ((size_t)b * NN + nW) * C + c] = acc[i];
        }
    }
}

// ---------------- gate: zr = sigmoid(per-node GEMM) ; write zh = z*h, r ----------------
template<int CIN>
__global__ void k_gate(int t, size_t woff, size_t boff) {
    constexpr int C = CIN + HH;
    constexpr int C2 = 2 * C;
    constexpr int O = 2 * HH;         // 128
    int n = blockIdx.x;
    int bg = blockIdx.y;              // 0..1 -> 16 batches per block
    int o = threadIdx.x & (O - 1);
    int sub = threadIdx.x >> 7;       // 0..1 -> 8 batches each
    __shared__ float xg[16][C2];
    for (int idx = threadIdx.x; idx < 16 * C2; idx += 256) {
        int bl = idx / C2, ki = idx - bl * C2;
        int b = bg * 16 + bl;
        float v;
        if (ki < C) {
            if (ki < CIN) {
                if constexpr (CIN == 1) v = g_buf[S_SRC + ((size_t)b * TT + t) * NN + n];
                else v = g_buf[OFF_OUT0 + (((size_t)b * TT + t) * NN + n) * HH + ki];
            } else {
                v = g_buf[OFF_H + ((size_t)b * NN + n) * HH + (ki - CIN)];
            }
        } else {
            v = g_buf[OFF_AGG_G + ((size_t)b * NN + n) * C + (ki - C)];
        }
        xg[bl][ki] = v;
    }
    __syncthreads();
    float bias = g_buf[boff + (size_t)n * O + o];
    float acc[8];
    #pragma unroll
    for (int j = 0; j < 8; j++) acc[j] = bias;
    const float* W = g_buf + woff + (size_t)n * C2 * O;
    int blb = sub * 8;
    for (int ki = 0; ki < C2; ki++) {
        float w = W[(size_t)ki * O + o];
        #pragma unroll
        for (int j = 0; j < 8; j++) acc[j] += xg[blb + j][ki] * w;
    }
    #pragma unroll
    for (int j = 0; j < 8; j++) {
        int b = bg * 16 + blb + j;
        float zr = 1.f / (1.f + expf(-acc[j]));
        size_t base = ((size_t)b * NN + n) * HH;
        if (o < HH) g_buf[OFF_ZH + base + o] = zr * g_buf[OFF_H + base + o];
        else        g_buf[OFF_R + base + (o - HH)] = zr;
    }
}

// ---------------- update: hc = tanh(per-node GEMM) ; h = r*h + (1-r)*hc ----------------
template<int CIN, bool WOUT>
__global__ void k_upd(int t, size_t woff, size_t boff) {
    constexpr int C = CIN + HH;
    constexpr int C2 = 2 * C;
    constexpr int O = HH;             // 64
    int n = blockIdx.x;
    int bg = blockIdx.y;
    int o = threadIdx.x & 63;
    int sub = threadIdx.x >> 6;       // 0..3 -> 4 batches each
    __shared__ float xg[16][C2];
    for (int idx = threadIdx.x; idx < 16 * C2; idx += 256) {
        int bl = idx / C2, ki = idx - bl * C2;
        int b = bg * 16 + bl;
        float v;
        if (ki < C) {
            if (ki < CIN) {
                if constexpr (CIN == 1) v = g_buf[S_SRC + ((size_t)b * TT + t) * NN + n];
                else v = g_buf[OFF_OUT0 + (((size_t)b * TT + t) * NN + n) * HH + ki];
            } else {
                v = g_buf[OFF_ZH + ((size_t)b * NN + n) * HH + (ki - CIN)];
            }
        } else {
            v = g_buf[OFF_AGG_U + ((size_t)b * NN + n) * C + (ki - C)];
        }
        xg[bl][ki] = v;
    }
    __syncthreads();
    float bias = g_buf[boff + (size_t)n * O + o];
    float acc[4];
    #pragma unroll
    for (int j = 0; j < 4; j++) acc[j] = bias;
    const float* W = g_buf + woff + (size_t)n * C2 * O;
    int blb = sub * 4;
    for (int ki = 0; ki < C2; ki++) {
        float w = W[(size_t)ki * O + o];
        #pragma unroll
        for (int j = 0; j < 4; j++) acc[j] += xg[blb + j][ki] * w;
    }
    #pragma unroll
    for (int j = 0; j < 4; j++) {
        int b = bg * 16 + blb + j;
        size_t base = ((size_t)b * NN + n) * HH + o;
        float hc = tanhf(acc[j]);
        float r = g_buf[OFF_R + base];
        float hold = g_buf[OFF_H + base];
        float hn = r * hold + (1.f - r) * hc;
        g_buf[OFF_H + base] = hn;
        if constexpr (WOUT) g_buf[OFF_OUT0 + (((size_t)b * TT + t) * NN + n) * HH + o] = hn;
    }
}

// ---------------- fused attention (only t=T-1 output needed) + LN1 ----------------
__global__ void k_attn() {
    int n = blockIdx.x, b = blockIdx.y;
    int h = threadIdx.x;              // 64 = 1 wave
    __shared__ float x[TT][HH], kk[TT][HH], vv[TT][HH], q[HH], o1[HH];
    __shared__ float sc[HEADS][TT], aw[HEADS][TT];
    float mw = g_buf[S_MLW + h];
    float mb = g_buf[S_MLB + h];
    #pragma unroll
    for (int tt = 0; tt < TT; tt++) {
        float s = g_buf[S_SRC + ((size_t)b * TT + tt) * NN + n];
        x[tt][h] = s * mw + mb + g_buf[OFF_PE + tt * HH + h];
    }
    __syncthreads();
    float ka[TT], va[TT];
    #pragma unroll
    for (int tt = 0; tt < TT; tt++) { ka[tt] = g_buf[S_BK + h]; va[tt] = g_buf[S_BV + h]; }
    float qa = g_buf[S_BQ + h];
    for (int i = 0; i < HH; i++) {
        float wkv = g_buf[S_WK + i * HH + h];
        float wvv = g_buf[S_WV + i * HH + h];
        qa += x[TT - 1][i] * g_buf[S_WQ + i * HH + h];
        #pragma unroll
        for (int tt = 0; tt < TT; tt++) {
            float xv = x[tt][i];
            ka[tt] += xv * wkv;
            va[tt] += xv * wvv;
        }
    }
    #pragma unroll
    for (int tt = 0; tt < TT; tt++) { kk[tt][h] = ka[tt]; vv[tt][h] = va[tt]; }
    q[h] = qa;
    __syncthreads();
    if (h < HEADS * TT) {
        int head = h / TT, ts = h - head * TT;
        float s = 0.f;
        #pragma unroll
        for (int d = 0; d < HD; d++) s += q[head * HD + d] * kk[ts][head * HD + d];
        sc[head][ts] = s * 0.25f;     // 1/sqrt(16)
    }
    __syncthreads();
    if (h < HEADS * TT) {
        int head = h / TT, ts = h - head * TT;
        float mx = -1e30f;
        #pragma unroll
        for (int j = 0; j < TT; j++) mx = fmaxf(mx, sc[head][j]);
        float sm = 0.f;
        #pragma unroll
        for (int j = 0; j < TT; j++) sm += expf(sc[head][j] - mx);
        aw[head][ts] = expf(sc[head][ts] - mx) / sm;
    }
    __syncthreads();
    int head = h >> 4;
    float oa = 0.f;
    #pragma unroll
    for (int tt = 0; tt < TT; tt++) oa += aw[head][tt] * vv[tt][h];
    o1[h] = oa;
    __syncthreads();
    float acc = g_buf[S_BO + h];
    for (int i = 0; i < HH; i++) acc += o1[i] * g_buf[S_WO + i * HH + h];
    float res = x[TT - 1][h] + acc;
    float mean = wave_sum(res) * (1.f / 64.f);
    float dv = res - mean;
    float var = wave_sum(dv * dv) * (1.f / 64.f);
    float ln = dv * rsqrtf(var + 1e-5f) * g_buf[S_L1G + h] + g_buf[S_L1B + h];
    g_buf[OFF_OLN + ((size_t)b * NN + n) * HH + h] = ln;
}

// ---------------- FFN (t=T-1 tokens only) + LN2 ----------------
__global__ void k_ffn() {
    int tok0 = blockIdx.x * 4;        // 9824 tokens = 2456 * 4
    int tid = threadIdx.x;            // 256
    __shared__ float ox[4][HH];
    __shared__ float hid[4][1024];
    for (int idx = tid; idx < 4 * HH; idx += 256) {
        int tk = idx >> 6, hh = idx & 63;
        ox[tk][hh] = g_buf[OFF_OLN + (size_t)(tok0 + tk) * HH + hh];
    }
    __syncthreads();
    #pragma unroll
    for (int p = 0; p < 4; p++) {
        int j = tid + 256 * p;
        float bj = g_buf[S_FB1 + j];
        float a0 = bj, a1 = bj, a2 = bj, a3 = bj;
        for (int i = 0; i < HH; i++) {
            float w = g_buf[S_FW1 + (size_t)i * 1024 + j];
            a0 += ox[0][i] * w; a1 += ox[1][i] * w; a2 += ox[2][i] * w; a3 += ox[3][i] * w;
        }
        hid[0][j] = fmaxf(a0, 0.f); hid[1][j] = fmaxf(a1, 0.f);
        hid[2][j] = fmaxf(a2, 0.f); hid[3][j] = fmaxf(a3, 0.f);
    }
    __syncthreads();
    int tk = tid >> 6, hh = tid & 63; // one wave per token
    float acc = g_buf[S_FB2 + hh];
    for (int j = 0; j < 1024; j++) acc += hid[tk][j] * g_buf[S_FW2 + (size_t)j * HH + hh];
    float res = ox[tk][hh] + acc;
    float mean = wave_sum(res) * (1.f / 64.f);
    float dv = res - mean;
    float var = wave_sum(dv * dv) * (1.f / 64.f);
    float ln = dv * rsqrtf(var + 1e-5f) * g_buf[S_L2G + hh] + g_buf[S_L2B + hh];
    g_buf[OFF_O2 + (size_t)(tok0 + tk) * HH + hh] = ln;
}

// ---------------- final combine + horizon conv (dtype-flag-aware store) ----------------
__global__ void k_final(void* out) {
    int n = blockIdx.x, b = blockIdx.y;
    int h = threadIdx.x;              // 64
    __shared__ float comb[HH];
    size_t base = ((size_t)b * NN + n) * HH + h;
    comb[h] = g_buf[OFF_H + base] * g_buf[S_WS + n * HH + h]
            + g_buf[OFF_O2 + base] * g_buf[S_WT + n * HH + h];
    __syncthreads();
    if (h < HORIZON) {
        float acc = g_buf[S_CB + h];
        #pragma unroll
        for (int i = 0; i < HH; i++) acc += comb[i] * g_buf[S_CW + h * HH + i];
        size_t oi = ((size_t)b * HORIZON + h) * NN + n;
        if (g_flag) ((bf16*)out)[oi] = __float2bfloat16(acc);
        else        ((float*)out)[oi] = acc;
    }
}

extern "C" void kernel_launch(void* const* d_in, const int* in_sizes, int n_in,
                              void* d_out, int out_size, void* d_ws, size_t ws_size,
                              hipStream_t stream) {
    PtrPack pk;
    for (int i = 0; i < 32; i++) pk.p[i] = d_in[i];

    k_detect<<<1, 64, 0, stream>>>(d_in[1]);
    k_ingest<<<4133, 256, 0, stream>>>(pk);
    k_adj<<<NN, 512, 0, stream>>>();
    k_nodew_all<<<89337, 256, 0, stream>>>();
    k_pe<<<1, 768, 0, stream>>>();

    // ---- GRU layer 0 (C_in = 1) ----
    k_zero<<<2456, 256, 0, stream>>>(OFF_H, 628736);
    for (int t = 0; t < TT; t++) {
        k_agg<1><<<dim3(20, BB), 128, 0, stream>>>(t, OFF_H, OFF_AGG_G);
        k_gate<1><<<dim3(NN, 2), 256, 0, stream>>>(t, OFF_WG0n, OFF_BG0n);
        k_agg<1><<<dim3(20, BB), 128, 0, stream>>>(t, OFF_ZH, OFF_AGG_U);
        k_upd<1, true><<<dim3(NN, 2), 256, 0, stream>>>(t, OFF_WU0n, OFF_BU0n);
    }
    // ---- GRU layer 1 (C_in = 64) ----
    k_zero<<<2456, 256, 0, stream>>>(OFF_H, 628736);
    for (int t = 0; t < TT; t++) {
        k_agg<64><<<dim3(20, BB), 128, 0, stream>>>(t, OFF_H, OFF_AGG_G);
        k_gate<64><<<dim3(NN, 2), 256, 0, stream>>>(t, OFF_WG1n, OFF_BG1n);
        k_agg<64><<<dim3(20, BB), 128, 0, stream>>>(t, OFF_ZH, OFF_AGG_U);
        k_upd<64, false><<<dim3(NN, 2), 256, 0, stream>>>(t, OFF_WU1n, OFF_BU1n);
    }
    // ---- transformer branch (only t = T-1 needed downstream) ----
    k_attn<<<dim3(NN, BB), 64, 0, stream>>>();
    k_ffn<<<2456, 256, 0, stream>>>();
    // ---- combine + conv ----
    k_final<<<dim3(NN, BB), 64, 0, stream>>>(d_out);
}

// Round 4
// 4888.961 us; speedup vs baseline: 1.0232x; 1.0232x over previous
//
#include <hip/hip_runtime.h>
#include <hip/hip_bf16.h>

typedef __hip_bfloat16 bf16;

constexpr int NN = 307, TT = 12, BB = 32, HH = 64, EE = 10, HEADS = 4, HD = 16, HORIZON = 12;

// ---------------- staged fp32 input offsets ----------------
constexpr int S_SRC = 0,       S_EMB = 117888,  S_GW0 = 120958,  S_GB0 = 287358,
              S_UW0 = 288638,  S_UB0 = 371838,  S_GW1 = 372478,  S_GB1 = 700158,
              S_UW1 = 701438,  S_UB1 = 865278,  S_MLW = 865918,  S_MLB = 865982,
              S_WQ  = 866046,  S_BQ  = 870142,  S_WK  = 870206,  S_BK  = 874302,
              S_WV  = 874366,  S_BV  = 878462,  S_WO  = 878526,  S_BO  = 882622,
              S_FW1 = 882686,  S_FB1 = 948222,  S_FW2 = 949246,  S_FB2 = 1014782,
              S_L1G = 1014846, S_L1B = 1014910, S_L2G = 1014974, S_L2B = 1015038,
              S_WS  = 1015102, S_WT  = 1034750, S_CW  = 1054398, S_CB  = 1055166;
constexpr size_t S_TOT = 1055178;

// ---------------- fp32 work regions ----------------
constexpr size_t OFF_A    = 1055178;   // 307*307
constexpr size_t OFF_OUT0 = 1149427;   // [t][n][b][c] 12*307*2048
constexpr size_t OFF_H    = 8694259;   // [n][b][c] 307*2048
constexpr size_t OFF_ZH   = 9322995;
constexpr size_t OFF_R    = 9951731;
constexpr size_t OFF_AGG  = 10580467;  // shared by aggH / aggZH (sequential)
constexpr size_t OFF_AX0  = 11209203;  // [t][n][b] 12*307*32
constexpr size_t OFF_AX1  = 11327091;  // [t][n][b][c] 12*307*2048
constexpr size_t OFF_PE   = 18871923;  // 12*64
constexpr size_t OFF_OLN  = 18872691;  // [b*307+n][c]
constexpr size_t OFF_O2   = 19501427;
constexpr size_t OFF_WB   = 20130164;  // fp32 per-node GRU weights (22870272 floats)
constexpr size_t G_TOTAL  = 43000436;  // ~172 MB

// element bases inside WB area (cumulative, same order as SEGC) — fp32 now.
// NOTE r3->r4: bf16 weight storage amplified through the 12-step x 2-layer scan
// (per-step Jacobian gain ~1.25) to absmax 0.19; fp32 weights are required.
constexpr size_t WG0B = 0,        BG0B = 5108480,  WU0B = 5147776,  BU0B = 7702016,
                 WG1B = 7721664,  BG1B = 17781440, WU1B = 17820736, BU1B = 22850624;

__device__ float g_buf[G_TOTAL];
__device__ int g_flag;   // 1 = inputs are bf16, 0 = fp32

__device__ __forceinline__ float b2f(bf16 v) { return __bfloat162float(v); }

__device__ __forceinline__ float wave_sum(float v) {
    #pragma unroll
    for (int off = 32; off > 0; off >>= 1) v += __shfl_xor(v, off, 64);
    return v;
}

// ---------------- dtype detection ----------------
__global__ void k_detect(const void* emb_raw) {
    const bf16* p = (const bf16*)emb_raw;
    int lane = threadIdx.x;
    float v = __bfloat162float(p[lane]);
    bool plaus = (v == v) && (fabsf(v) <= 1e4f) && (v == 0.f || fabsf(v) >= 1e-4f);
    float c = wave_sum(plaus ? 1.f : 0.f);
    if (lane == 0) g_flag = (c >= 52.f) ? 1 : 0;
}

// ---------------- ingest all inputs as fp32 ----------------
struct PtrPack { const void* p[32]; };
__device__ const int D_CNT[32] = {117888,3070,166400,1280,83200,640,327680,1280,163840,640,
                                  64,64,4096,64,4096,64,4096,64,4096,64,
                                  65536,1024,65536,64,64,64,64,64,19648,19648,768,12};
__device__ const int D_OFF[32] = {S_SRC,S_EMB,S_GW0,S_GB0,S_UW0,S_UB0,S_GW1,S_GB1,S_UW1,S_UB1,
                                  S_MLW,S_MLB,S_WQ,S_BQ,S_WK,S_BK,S_WV,S_BV,S_WO,S_BO,
                                  S_FW1,S_FB1,S_FW2,S_FB2,S_L1G,S_L1B,S_L2G,S_L2B,S_WS,S_WT,S_CW,S_CB};
__device__ const int D_CHK[33] = {0,461,473,1123,1128,1453,1456,2736,2741,3381,3384,3385,3386,
                                  3402,3403,3419,3420,3436,3437,3453,3454,3710,3714,3970,3971,
                                  3972,3973,3974,3975,4052,4129,4132,4133};

__global__ void k_ingest(PtrPack pk) {
    int bid = blockIdx.x;
    int s = 0;
    while (s < 31 && bid >= D_CHK[s + 1]) s++;
    int i = (bid - D_CHK[s]) * 256 + threadIdx.x;
    if (i >= D_CNT[s]) return;
    float v;
    if (g_flag) v = __bfloat162float(((const bf16*)pk.p[s])[i]);
    else        v = ((const float*)pk.p[s])[i];
    g_buf[(size_t)D_OFF[s] + i] = v;
}

// ---------------- adjacency ----------------
__global__ void k_adj() {
    int n = blockIdx.x;
    int tid = threadIdx.x;            // 512
    __shared__ float en[EE];
    __shared__ float red[512];
    if (tid < EE) en[tid] = g_buf[S_EMB + n * EE + tid];
    __syncthreads();
    bool act = tid < NN;
    float d = 0.f;
    if (act) {
        #pragma unroll
        for (int e = 0; e < EE; e++) d += en[e] * g_buf[S_EMB + tid * EE + e];
        d = fmaxf(d, 0.f);
    }
    red[tid] = act ? d : -1e30f;
    __syncthreads();
    for (int s = 256; s > 0; s >>= 1) { if (tid < s) red[tid] = fmaxf(red[tid], red[tid + s]); __syncthreads(); }
    float mx = red[0];
    __syncthreads();
    float ex = act ? expf(d - mx) : 0.f;
    red[tid] = ex;
    __syncthreads();
    for (int s = 256; s > 0; s >>= 1) { if (tid < s) red[tid] += red[tid + s]; __syncthreads(); }
    float inv = 1.f / red[0];
    if (act) g_buf[OFF_A + (size_t)n * NN + tid] = ex * inv;
}

// ---------------- per-node GRU weights -> fp32 ----------------
__device__ const unsigned SEGC[9] = {0u,5108480u,5147776u,7702016u,7721664u,17781440u,17820736u,22850624u,22870272u};
__device__ const int SEGJ[8]      = {16640,128,8320,64,32768,128,16384,64};
__device__ const int SEGS[8]      = {S_GW0,S_GB0,S_UW0,S_UB0,S_GW1,S_GB1,S_UW1,S_UB1};

__global__ void k_nodew_all() {
    unsigned idx = blockIdx.x * 256u + threadIdx.x;
    if (idx >= 22870272u) return;
    int s = 0;
    while (s < 7 && idx >= SEGC[s + 1]) s++;
    unsigned rem = idx - SEGC[s];
    unsigned J = (unsigned)SEGJ[s];
    unsigned n = rem / J;
    unsigned j = rem - n * J;
    float acc = 0.f;
    const float* eb = g_buf + S_EMB + n * EE;
    const float* w  = g_buf + SEGS[s];
    #pragma unroll
    for (int e = 0; e < EE; e++) acc += eb[e] * w[(size_t)e * J + j];
    g_buf[OFF_WB + SEGC[s] + (size_t)n * J + j] = acc;
}

// ---------------- positional embedding ----------------
__global__ void k_pe() {
    int tid = threadIdx.x;            // 768
    int t = tid >> 6, h = tid & 63;
    float ex = (float)(h & ~1) / 64.f;
    float ang = (float)t * powf(10000.f, -ex);
    g_buf[OFF_PE + tid] = (h & 1) ? cosf(ang) : sinf(ang);
}

__global__ void k_zero(size_t off, int cnt) {
    int i = blockIdx.x * 256 + threadIdx.x;
    if (i < cnt) g_buf[off + i] = 0.f;
}

// ---------------- AX0[t][n][b] = sum_m A[n,m] * src[b,t,m] ----------------
__global__ __launch_bounds__(256) void k_ax0() {
    int t = blockIdx.y;
    int n0 = blockIdx.x * 8;
    int b = threadIdx.x & 31, nl = threadIdx.x >> 5;
    __shared__ float As[8][68];
    __shared__ float xs[32][65];
    float acc = 0.f;
    for (int m0 = 0; m0 < NN; m0 += 64) {
        int jend = min(64, NN - m0);
        for (int idx = threadIdx.x; idx < 8 * 64; idx += 256) {
            int i = idx >> 6, jj = idx & 63;
            int n = n0 + i, m = m0 + jj;
            As[i][jj] = (n < NN && m < NN) ? g_buf[OFF_A + (size_t)n * NN + m] : 0.f;
        }
        for (int idx = threadIdx.x; idx < 32 * 64; idx += 256) {
            int bb = idx >> 6, jj = idx & 63;
            int m = m0 + jj;
            xs[bb][jj] = (m < NN) ? g_buf[S_SRC + ((size_t)bb * TT + t) * NN + m] : 0.f;
        }
        __syncthreads();
        for (int jj = 0; jj < jend; jj++) acc += As[nl][jj] * xs[b][jj];
        __syncthreads();
    }
    int n = n0 + nl;
    if (n < NN) g_buf[OFF_AX0 + ((size_t)t * NN + n) * 32 + b] = acc;
}

// ---------------- agg: dst[n, col] = sum_m A[n,m] * srcrows[m, col], cols = 2048 ----------------
__global__ __launch_bounds__(256) void k_aggmat(size_t srcOff, size_t dstOff, size_t srcTS, size_t dstTS) {
    int z = blockIdx.z;
    const float* srcp = g_buf + srcOff + (size_t)z * srcTS;
    float* dstp = g_buf + dstOff + (size_t)z * dstTS;
    int n0 = blockIdx.x * 16;
    int col = blockIdx.y * 256 + threadIdx.x;
    __shared__ float At[16][308];
    for (int idx = threadIdx.x; idx < 16 * 307; idx += 256) {
        int i = idx / 307, m = idx - i * 307;
        int n = n0 + i;
        At[i][m] = (n < NN) ? g_buf[OFF_A + (size_t)n * NN + m] : 0.f;
    }
    __syncthreads();
    float acc[16];
    #pragma unroll
    for (int i = 0; i < 16; i++) acc[i] = 0.f;
    #pragma unroll 4
    for (int m = 0; m < NN; m++) {
        float hv = srcp[(size_t)m * 2048 + col];
        #pragma unroll
        for (int i = 0; i < 16; i++) acc[i] += At[i][m] * hv;
    }
    #pragma unroll
    for (int i = 0; i < 16; i++) {
        int n = n0 + i;
        if (n < NN) dstp[(size_t)n * 2048 + col] = acc[i];
    }
}

// ---------------- gate: z,r = sigmoid(per-node GEMM); write zh, r ----------------
template<int CIN>
__global__ __launch_bounds__(256) void k_gate(int t) {
    constexpr int C = CIN + HH;
    constexpr int C2 = 2 * C;
    constexpr int C2P = (C2 + 3) & ~3;
    int n = blockIdx.x;
    __shared__ float xg[32][C2P];
    for (int idx = threadIdx.x; idx < 32 * C2; idx += 256) {
        int bl = idx / C2, ki = idx - bl * C2;
        float v;
        if constexpr (CIN == 64) {
            int seg = ki >> 6, c = ki & 63;
            if (seg == 0)      v = g_buf[OFF_OUT0 + (((size_t)t * NN + n) * 32 + bl) * 64 + c];
            else if (seg == 1) v = g_buf[OFF_H   + ((size_t)n * 32 + bl) * 64 + c];
            else if (seg == 2) v = g_buf[OFF_AX1 + (((size_t)t * NN + n) * 32 + bl) * 64 + c];
            else               v = g_buf[OFF_AGG + ((size_t)n * 32 + bl) * 64 + c];
        } else {
            if (ki == 0)       v = g_buf[S_SRC + ((size_t)bl * TT + t) * NN + n];
            else if (ki < 65)  v = g_buf[OFF_H + ((size_t)n * 32 + bl) * 64 + (ki - 1)];
            else if (ki == 65) v = g_buf[OFF_AX0 + ((size_t)t * NN + n) * 32 + bl];
            else               v = g_buf[OFF_AGG + ((size_t)n * 32 + bl) * 64 + (ki - 66)];
        }
        xg[bl][ki] = v;
    }
    __syncthreads();
    int o = threadIdx.x & 63;
    int bl0 = (threadIdx.x >> 6) * 8;
    const float* W  = g_buf + OFF_WB + (CIN == 64 ? WG1B : WG0B) + (size_t)n * C2 * 128;
    const float* Bb = g_buf + OFF_WB + (CIN == 64 ? BG1B : BG0B) + (size_t)n * 128;
    float bz = Bb[o], br = Bb[o + 64];
    float accz[8], accr[8];
    #pragma unroll
    for (int j = 0; j < 8; j++) { accz[j] = bz; accr[j] = br; }
    #pragma unroll 4
    for (int ki = 0; ki < C2; ki++) {
        float w0 = W[ki * 128 + o];
        float w1 = W[ki * 128 + o + 64];
        #pragma unroll
        for (int j = 0; j < 8; j++) {
            float xv = xg[bl0 + j][ki];
            accz[j] += xv * w0;
            accr[j] += xv * w1;
        }
    }
    #pragma unroll
    for (int j = 0; j < 8; j++) {
        int b = bl0 + j;
        float z = 1.f / (1.f + expf(-accz[j]));
        float r = 1.f / (1.f + expf(-accr[j]));
        float hv = xg[b][(CIN == 64 ? 64 : 1) + o];
        size_t base = ((size_t)n * 32 + b) * 64 + o;
        g_buf[OFF_ZH + base] = z * hv;
        g_buf[OFF_R + base]  = r;
    }
}

// ---------------- update: hc = tanh(per-node GEMM); h = r*h + (1-r)*hc ----------------
template<int CIN, bool WOUT>
__global__ __launch_bounds__(256) void k_upd(int t) {
    constexpr int C = CIN + HH;
    constexpr int C2 = 2 * C;
    constexpr int C2P = (C2 + 3) & ~3;
    int n = blockIdx.x;
    __shared__ float xg[32][C2P];
    for (int idx = threadIdx.x; idx < 32 * C2; idx += 256) {
        int bl = idx / C2, ki = idx - bl * C2;
        float v;
        if constexpr (CIN == 64) {
            int seg = ki >> 6, c = ki & 63;
            if (seg == 0)      v = g_buf[OFF_OUT0 + (((size_t)t * NN + n) * 32 + bl) * 64 + c];
            else if (seg == 1) v = g_buf[OFF_ZH  + ((size_t)n * 32 + bl) * 64 + c];
            else if (seg == 2) v = g_buf[OFF_AX1 + (((size_t)t * NN + n) * 32 + bl) * 64 + c];
            else               v = g_buf[OFF_AGG + ((size_t)n * 32 + bl) * 64 + c];
        } else {
            if (ki == 0)       v = g_buf[S_SRC + ((size_t)bl * TT + t) * NN + n];
            else if (ki < 65)  v = g_buf[OFF_ZH + ((size_t)n * 32 + bl) * 64 + (ki - 1)];
            else if (ki == 65) v = g_buf[OFF_AX0 + ((size_t)t * NN + n) * 32 + bl];
            else               v = g_buf[OFF_AGG + ((size_t)n * 32 + bl) * 64 + (ki - 66)];
        }
        xg[bl][ki] = v;
    }
    __syncthreads();
    int o = threadIdx.x & 63;
    int bl0 = (threadIdx.x >> 6) * 8;
    const float* W  = g_buf + OFF_WB + (CIN == 64 ? WU1B : WU0B) + (size_t)n * C2 * 64;
    const float* Bb = g_buf + OFF_WB + (CIN == 64 ? BU1B : BU0B) + (size_t)n * 64;
    float bu = Bb[o];
    float acc[8];
    #pragma unroll
    for (int j = 0; j < 8; j++) acc[j] = bu;
    #pragma unroll 4
    for (int ki = 0; ki < C2; ki++) {
        float w = W[ki * 64 + o];
        #pragma unroll
        for (int j = 0; j < 8; j++) acc[j] += xg[bl0 + j][ki] * w;
    }
    #pragma unroll
    for (int j = 0; j < 8; j++) {
        int b = bl0 + j;
        size_t base = ((size_t)n * 32 + b) * 64 + o;
        float hc = tanhf(acc[j]);
        float r = g_buf[OFF_R + base];
        float hold = g_buf[OFF_H + base];
        float hn = r * hold + (1.f - r) * hc;
        g_buf[OFF_H + base] = hn;
        if constexpr (WOUT)
            g_buf[OFF_OUT0 + (((size_t)t * NN + n) * 32 + b) * 64 + o] = hn;
    }
}

// ---------------- fused attention (t=T-1 only) + LN1; 4 (b,n) per block ----------------
__global__ __launch_bounds__(256) void k_attn() {
    int wid = threadIdx.x >> 6;
    int lane = threadIdx.x & 63;
    int g = blockIdx.x * 4 + wid;     // 0..9823
    int b = g / NN, n = g - b * NN;
    __shared__ float x[4][TT][HH], kk[4][TT][HH], vv[4][TT][HH];
    __shared__ float q[4][HH], o1[4][HH], sc[4][HEADS][TT], aw[4][HEADS][TT];
    float mw = g_buf[S_MLW + lane];
    float mb = g_buf[S_MLB + lane];
    #pragma unroll
    for (int tt = 0; tt < TT; tt++) {
        float s = g_buf[S_SRC + ((size_t)b * TT + tt) * NN + n];
        x[wid][tt][lane] = s * mw + mb + g_buf[OFF_PE + tt * HH + lane];
    }
    __syncthreads();
    float ka[TT], va[TT];
    #pragma unroll
    for (int tt = 0; tt < TT; tt++) { ka[tt] = g_buf[S_BK + lane]; va[tt] = g_buf[S_BV + lane]; }
    float qa = g_buf[S_BQ + lane];
    for (int i = 0; i < HH; i++) {
        float wkv = g_buf[S_WK + i * HH + lane];
        float wvv = g_buf[S_WV + i * HH + lane];
        qa += x[wid][TT - 1][i] * g_buf[S_WQ + i * HH + lane];
        #pragma unroll
        for (int tt = 0; tt < TT; tt++) {
            float xv = x[wid][tt][i];
            ka[tt] += xv * wkv;
            va[tt] += xv * wvv;
        }
    }
    #pragma unroll
    for (int tt = 0; tt < TT; tt++) { kk[wid][tt][lane] = ka[tt]; vv[wid][tt][lane] = va[tt]; }
    q[wid][lane] = qa;
    __syncthreads();
    if (lane < HEADS * TT) {
        int head = lane / TT, ts = lane - head * TT;
        float s = 0.f;
        #pragma unroll
        for (int d = 0; d < HD; d++) s += q[wid][head * HD + d] * kk[wid][ts][head * HD + d];
        sc[wid][head][ts] = s * 0.25f;
    }
    __syncthreads();
    if (lane < HEADS * TT) {
        int head = lane / TT, ts = lane - head * TT;
        float mx = -1e30f;
        #pragma unroll
        for (int j = 0; j < TT; j++) mx = fmaxf(mx, sc[wid][head][j]);
        float sm = 0.f;
        #pragma unroll
        for (int j = 0; j < TT; j++) sm += expf(sc[wid][head][j] - mx);
        aw[wid][head][ts] = expf(sc[wid][head][ts] - mx) / sm;
    }
    __syncthreads();
    int head = lane >> 4;
    float oa = 0.f;
    #pragma unroll
    for (int tt = 0; tt < TT; tt++) oa += aw[wid][head][tt] * vv[wid][tt][lane];
    o1[wid][lane] = oa;
    __syncthreads();
    float acc = g_buf[S_BO + lane];
    for (int i = 0; i < HH; i++) acc += o1[wid][i] * g_buf[S_WO + i * HH + lane];
    float res = x[wid][TT - 1][lane] + acc;
    float mean = wave_sum(res) * (1.f / 64.f);
    float dv = res - mean;
    float var = wave_sum(dv * dv) * (1.f / 64.f);
    float ln = dv * rsqrtf(var + 1e-5f) * g_buf[S_L1G + lane] + g_buf[S_L1B + lane];
    g_buf[OFF_OLN + ((size_t)b * NN + n) * HH + lane] = ln;
}

// ---------------- FFN + LN2; 8 tokens per block ----------------
__global__ __launch_bounds__(256) void k_ffn() {
    int tok0 = blockIdx.x * 8;        // 9824 = 1228 * 8
    int tid = threadIdx.x;
    __shared__ float ox[8][HH];
    __shared__ float hid[8][1024];
    for (int idx = tid; idx < 8 * HH; idx += 256) {
        int tk = idx >> 6, hh = idx & 63;
        ox[tk][hh] = g_buf[OFF_OLN + (size_t)(tok0 + tk) * HH + hh];
    }
    __syncthreads();
    #pragma unroll
    for (int p = 0; p < 4; p++) {
        int j = tid + 256 * p;
        float bj = g_buf[S_FB1 + j];
        float a[8];
        #pragma unroll
        for (int tk = 0; tk < 8; tk++) a[tk] = bj;
        for (int i = 0; i < HH; i++) {
            float w = g_buf[S_FW1 + (size_t)i * 1024 + j];
            #pragma unroll
            for (int tk = 0; tk < 8; tk++) a[tk] += ox[tk][i] * w;
        }
        #pragma unroll
        for (int tk = 0; tk < 8; tk++) hid[tk][j] = fmaxf(a[tk], 0.f);
    }
    __syncthreads();
    int tk = tid >> 6, hh = tid & 63; // tokens tk and tk+4 per thread
    float acc0 = g_buf[S_FB2 + hh], acc1 = acc0;
    for (int j = 0; j < 1024; j++) {
        float w = g_buf[S_FW2 + (size_t)j * HH + hh];
        acc0 += hid[tk][j] * w;
        acc1 += hid[tk + 4][j] * w;
    }
    #pragma unroll
    for (int ph = 0; ph < 2; ph++) {
        int tkk = tk + 4 * ph;
        float res = ox[tkk][hh] + (ph ? acc1 : acc0);
        float mean = wave_sum(res) * (1.f / 64.f);
        float dv = res - mean;
        float var = wave_sum(dv * dv) * (1.f / 64.f);
        float ln = dv * rsqrtf(var + 1e-5f) * g_buf[S_L2G + hh] + g_buf[S_L2B + hh];
        g_buf[OFF_O2 + (size_t)(tok0 + tkk) * HH + hh] = ln;
    }
}

// ---------------- final combine + horizon conv ----------------
__global__ void k_final(void* out) {
    int n = blockIdx.x, b = blockIdx.y;
    int h = threadIdx.x;              // 64
    __shared__ float comb[HH];
    comb[h] = g_buf[OFF_H + ((size_t)n * 32 + b) * 64 + h] * g_buf[S_WS + n * HH + h]
            + g_buf[OFF_O2 + ((size_t)b * NN + n) * 64 + h] * g_buf[S_WT + n * HH + h];
    __syncthreads();
    if (h < HORIZON) {
        float acc = g_buf[S_CB + h];
        #pragma unroll
        for (int i = 0; i < HH; i++) acc += comb[i] * g_buf[S_CW + h * HH + i];
        size_t oi = ((size_t)b * HORIZON + h) * NN + n;
        if (g_flag) ((bf16*)out)[oi] = __float2bfloat16(acc);
        else        ((float*)out)[oi] = acc;
    }
}

extern "C" void kernel_launch(void* const* d_in, const int* in_sizes, int n_in,
                              void* d_out, int out_size, void* d_ws, size_t ws_size,
                              hipStream_t stream) {
    PtrPack pk;
    for (int i = 0; i < 32; i++) pk.p[i] = d_in[i];

    k_detect<<<1, 64, 0, stream>>>(d_in[1]);
    k_ingest<<<4133, 256, 0, stream>>>(pk);
    k_adj<<<NN, 512, 0, stream>>>();
    k_nodew_all<<<89337, 256, 0, stream>>>();
    k_pe<<<1, 768, 0, stream>>>();
    k_ax0<<<dim3(39, 12), 256, 0, stream>>>();   // 39*8 = 312 >= 307

    // ---- GRU layer 0 (C_in = 1) ----
    k_zero<<<2456, 256, 0, stream>>>(OFF_H, 628736);
    for (int t = 0; t < TT; t++) {
        k_aggmat<<<dim3(20, 8, 1), 256, 0, stream>>>(OFF_H, OFF_AGG, 0, 0);
        k_gate<1><<<NN, 256, 0, stream>>>(t);
        k_aggmat<<<dim3(20, 8, 1), 256, 0, stream>>>(OFF_ZH, OFF_AGG, 0, 0);
        k_upd<1, true><<<NN, 256, 0, stream>>>(t);
    }
    // ---- AX1[t] = A @ out0[t] for all t (parallel) ----
    k_aggmat<<<dim3(20, 8, 12), 256, 0, stream>>>(OFF_OUT0, OFF_AX1, 628736, 628736);
    // ---- GRU layer 1 (C_in = 64) ----
    k_zero<<<2456, 256, 0, stream>>>(OFF_H, 628736);
    for (int t = 0; t < TT; t++) {
        k_aggmat<<<dim3(20, 8, 1), 256, 0, stream>>>(OFF_H, OFF_AGG, 0, 0);
        k_gate<64><<<NN, 256, 0, stream>>>(t);
        k_aggmat<<<dim3(20, 8, 1), 256, 0, stream>>>(OFF_ZH, OFF_AGG, 0, 0);
        k_upd<64, false><<<NN, 256, 0, stream>>>(t);
    }
    // ---- transformer branch ----
    k_attn<<<2456, 256, 0, stream>>>();
    k_ffn<<<1228, 256, 0, stream>>>();
    // ---- combine + conv ----
    k_final<<<dim3(NN, BB), 64, 0, stream>>>(d_out);
}

// Round 5
// 4801.281 us; speedup vs baseline: 1.0419x; 1.0183x over previous
//
#include <hip/hip_runtime.h>
#include <hip/hip_bf16.h>

typedef __hip_bfloat16 bf16;

constexpr int NN = 307, TT = 12, BB = 32, HH = 64, EE = 10, HEADS = 4, HD = 16, HORIZON = 12;

// ---------------- staged fp32 input offsets ----------------
constexpr int S_SRC = 0,       S_EMB = 117888,  S_GW0 = 120958,  S_GB0 = 287358,
              S_UW0 = 288638,  S_UB0 = 371838,  S_GW1 = 372478,  S_GB1 = 700158,
              S_UW1 = 701438,  S_UB1 = 865278,  S_MLW = 865918,  S_MLB = 865982,
              S_WQ  = 866046,  S_BQ  = 870142,  S_WK  = 870206,  S_BK  = 874302,
              S_WV  = 874366,  S_BV  = 878462,  S_WO  = 878526,  S_BO  = 882622,
              S_FW1 = 882686,  S_FB1 = 948222,  S_FW2 = 949246,  S_FB2 = 1014782,
              S_L1G = 1014846, S_L1B = 1014910, S_L2G = 1014974, S_L2B = 1015038,
              S_WS  = 1015102, S_WT  = 1034750, S_CW  = 1054398, S_CB  = 1055166;
constexpr size_t S_TOT = 1055178;

// ---------------- fp32 work regions ----------------
constexpr size_t OFF_A    = 1055178;   // 307*307
constexpr size_t OFF_OUT0 = 1149427;   // [t][n][b][c] 12*307*2048
constexpr size_t OFF_H    = 8694259;   // [n][b][c] 307*2048
constexpr size_t OFF_ZH   = 9322995;
constexpr size_t OFF_R    = 9951731;
constexpr size_t OFF_AGG  = 10580467;  // shared by aggH / aggZH (sequential)
constexpr size_t OFF_AX0  = 11209203;  // [t][n][b] 12*307*32
constexpr size_t OFF_AX1  = 11327091;  // [t][n][b][c] 12*307*2048
constexpr size_t OFF_PE   = 18871923;  // 12*64
constexpr size_t OFF_OLN  = 18872691;  // [b*307+n][c]
constexpr size_t OFF_O2   = 19501427;
constexpr size_t OFF_WB   = 20130164;  // fp32 per-node GRU weights (22870272 floats)
constexpr size_t G_TOTAL  = 43000436;  // ~172 MB

// element bases inside WB area (cumulative). fp32 required: bf16 weights amplified
// through the 12-step x 2-layer scan (per-step gain ~1.25) to absmax 0.19 (r3).
constexpr size_t WG0B = 0,        BG0B = 5108480,  WU0B = 5147776,  BU0B = 7702016,
                 WG1B = 7721664,  BG1B = 17781440, WU1B = 17820736, BU1B = 22850624;

__device__ float g_buf[G_TOTAL];
__device__ int g_flag;   // 1 = inputs are bf16, 0 = fp32

__device__ __forceinline__ float wave_sum(float v) {
    #pragma unroll
    for (int off = 32; off > 0; off >>= 1) v += __shfl_xor(v, off, 64);
    return v;
}

// ---------------- dtype detection ----------------
__global__ void k_detect(const void* emb_raw) {
    const bf16* p = (const bf16*)emb_raw;
    int lane = threadIdx.x;
    float v = __bfloat162float(p[lane]);
    bool plaus = (v == v) && (fabsf(v) <= 1e4f) && (v == 0.f || fabsf(v) >= 1e-4f);
    float c = wave_sum(plaus ? 1.f : 0.f);
    if (lane == 0) g_flag = (c >= 52.f) ? 1 : 0;
}

// ---------------- ingest all inputs as fp32 ----------------
struct PtrPack { const void* p[32]; };
__device__ const int D_CNT[32] = {117888,3070,166400,1280,83200,640,327680,1280,163840,640,
                                  64,64,4096,64,4096,64,4096,64,4096,64,
                                  65536,1024,65536,64,64,64,64,64,19648,19648,768,12};
__device__ const int D_OFF[32] = {S_SRC,S_EMB,S_GW0,S_GB0,S_UW0,S_UB0,S_GW1,S_GB1,S_UW1,S_UB1,
                                  S_MLW,S_MLB,S_WQ,S_BQ,S_WK,S_BK,S_WV,S_BV,S_WO,S_BO,
                                  S_FW1,S_FB1,S_FW2,S_FB2,S_L1G,S_L1B,S_L2G,S_L2B,S_WS,S_WT,S_CW,S_CB};
__device__ const int D_CHK[33] = {0,461,473,1123,1128,1453,1456,2736,2741,3381,3384,3385,3386,
                                  3402,3403,3419,3420,3436,3437,3453,3454,3710,3714,3970,3971,
                                  3972,3973,3974,3975,4052,4129,4132,4133};

__global__ void k_ingest(PtrPack pk) {
    int bid = blockIdx.x;
    int s = 0;
    while (s < 31 && bid >= D_CHK[s + 1]) s++;
    int i = (bid - D_CHK[s]) * 256 + threadIdx.x;
    if (i >= D_CNT[s]) return;
    float v;
    if (g_flag) v = __bfloat162float(((const bf16*)pk.p[s])[i]);
    else        v = ((const float*)pk.p[s])[i];
    g_buf[(size_t)D_OFF[s] + i] = v;
}

// ---------------- adjacency ----------------
__global__ void k_adj() {
    int n = blockIdx.x;
    int tid = threadIdx.x;            // 512
    __shared__ float en[EE];
    __shared__ float red[512];
    if (tid < EE) en[tid] = g_buf[S_EMB + n * EE + tid];
    __syncthreads();
    bool act = tid < NN;
    float d = 0.f;
    if (act) {
        #pragma unroll
        for (int e = 0; e < EE; e++) d += en[e] * g_buf[S_EMB + tid * EE + e];
        d = fmaxf(d, 0.f);
    }
    red[tid] = act ? d : -1e30f;
    __syncthreads();
    for (int s = 256; s > 0; s >>= 1) { if (tid < s) red[tid] = fmaxf(red[tid], red[tid + s]); __syncthreads(); }
    float mx = red[0];
    __syncthreads();
    float ex = act ? expf(d - mx) : 0.f;
    red[tid] = ex;
    __syncthreads();
    for (int s = 256; s > 0; s >>= 1) { if (tid < s) red[tid] += red[tid + s]; __syncthreads(); }
    float inv = 1.f / red[0];
    if (act) g_buf[OFF_A + (size_t)n * NN + tid] = ex * inv;
}

// ---------------- per-node GRU weights -> fp32 ----------------
__device__ const unsigned SEGC[9] = {0u,5108480u,5147776u,7702016u,7721664u,17781440u,17820736u,22850624u,22870272u};
__device__ const int SEGJ[8]      = {16640,128,8320,64,32768,128,16384,64};
__device__ const int SEGS[8]      = {S_GW0,S_GB0,S_UW0,S_UB0,S_GW1,S_GB1,S_UW1,S_UB1};

__global__ void k_nodew_all() {
    unsigned idx = blockIdx.x * 256u + threadIdx.x;
    if (idx >= 22870272u) return;
    int s = 0;
    while (s < 7 && idx >= SEGC[s + 1]) s++;
    unsigned rem = idx - SEGC[s];
    unsigned J = (unsigned)SEGJ[s];
    unsigned n = rem / J;
    unsigned j = rem - n * J;
    float acc = 0.f;
    const float* eb = g_buf + S_EMB + n * EE;
    const float* w  = g_buf + SEGS[s];
    #pragma unroll
    for (int e = 0; e < EE; e++) acc += eb[e] * w[(size_t)e * J + j];
    g_buf[OFF_WB + SEGC[s] + (size_t)n * J + j] = acc;
}

// ---------------- positional embedding ----------------
__global__ void k_pe() {
    int tid = threadIdx.x;            // 768
    int t = tid >> 6, h = tid & 63;
    float ex = (float)(h & ~1) / 64.f;
    float ang = (float)t * powf(10000.f, -ex);
    g_buf[OFF_PE + tid] = (h & 1) ? cosf(ang) : sinf(ang);
}

__global__ void k_zero(size_t off, int cnt) {
    int i = blockIdx.x * 256 + threadIdx.x;
    if (i < cnt) g_buf[off + i] = 0.f;
}

// ---------------- AX0[t][n][b] = sum_m A[n,m] * src[b,t,m] ----------------
__global__ __launch_bounds__(256) void k_ax0() {
    int t = blockIdx.y;
    int n0 = blockIdx.x * 8;
    int b = threadIdx.x & 31, nl = threadIdx.x >> 5;
    __shared__ float As[8][68];
    __shared__ float xs[32][65];
    float acc = 0.f;
    for (int m0 = 0; m0 < NN; m0 += 64) {
        int jend = min(64, NN - m0);
        for (int idx = threadIdx.x; idx < 8 * 64; idx += 256) {
            int i = idx >> 6, jj = idx & 63;
            int n = n0 + i, m = m0 + jj;
            As[i][jj] = (n < NN && m < NN) ? g_buf[OFF_A + (size_t)n * NN + m] : 0.f;
        }
        for (int idx = threadIdx.x; idx < 32 * 64; idx += 256) {
            int bb = idx >> 6, jj = idx & 63;
            int m = m0 + jj;
            xs[bb][jj] = (m < NN) ? g_buf[S_SRC + ((size_t)bb * TT + t) * NN + m] : 0.f;
        }
        __syncthreads();
        for (int jj = 0; jj < jend; jj++) acc += As[nl][jj] * xs[b][jj];
        __syncthreads();
    }
    int n = n0 + nl;
    if (n < NN) g_buf[OFF_AX0 + ((size_t)t * NN + n) * 32 + b] = acc;
}

// ---------------- agg GEMM: dst[n, col] = sum_m A[n,m] * src[m, col] ----------------
// 64x64 tile, BK=32, 4x4 register tile per thread. grid (5, 32, z), block 256.
__global__ __launch_bounds__(256) void k_aggmat(size_t srcOff, size_t dstOff, size_t srcTS, size_t dstTS) {
    int z = blockIdx.z;
    const float* __restrict__ srcp = g_buf + srcOff + (size_t)z * srcTS;
    float* __restrict__ dstp = g_buf + dstOff + (size_t)z * dstTS;
    int n0 = blockIdx.x * 64;
    int col0 = blockIdx.y * 64;
    int tid = threadIdx.x;
    int tn = tid >> 4, tc = tid & 15;
    __shared__ float As[32][68];   // [k][n-local], pad 68 -> 16B-aligned rows, 2-way banks
    __shared__ float Xs[32][64];   // [k][c-local]
    float acc[4][4];
    #pragma unroll
    for (int i = 0; i < 4; i++)
        #pragma unroll
        for (int j = 0; j < 4; j++) acc[i][j] = 0.f;
    for (int k0 = 0; k0 < NN; k0 += 32) {
        // stage A^T tile (coalesced over m)
        for (int idx = tid; idx < 64 * 32; idx += 256) {
            int k = idx & 31, i = idx >> 5;
            int n = n0 + i, m = k0 + k;
            As[k][i] = (n < NN && m < NN) ? g_buf[OFF_A + (size_t)n * NN + m] : 0.f;
        }
        // stage X tile (coalesced over cols)
        for (int idx = tid; idx < 32 * 64; idx += 256) {
            int c = idx & 63, k = idx >> 6;
            int m = k0 + k;
            Xs[k][c] = (m < NN) ? srcp[(size_t)m * 2048 + col0 + c] : 0.f;
        }
        __syncthreads();
        #pragma unroll
        for (int k = 0; k < 32; k++) {
            float4 a4 = *(const float4*)&As[k][tn * 4];
            float4 x4 = *(const float4*)&Xs[k][tc * 4];
            const float* aa = (const float*)&a4;
            const float* xx = (const float*)&x4;
            #pragma unroll
            for (int i = 0; i < 4; i++)
                #pragma unroll
                for (int j = 0; j < 4; j++) acc[i][j] += aa[i] * xx[j];
        }
        __syncthreads();
    }
    #pragma unroll
    for (int i = 0; i < 4; i++) {
        int n = n0 + tn * 4 + i;
        if (n < NN) {
            float4 v = make_float4(acc[i][0], acc[i][1], acc[i][2], acc[i][3]);
            *(float4*)&dstp[(size_t)n * 2048 + col0 + tc * 4] = v;
        }
    }
}

// ---------------- gate: z,r = sigmoid(per-node GEMM); write zh, r ----------------
// W streamed through LDS in chunks (exactly-once global read, no 4x redundancy).
template<int CIN>
__global__ __launch_bounds__(256) void k_gate(int t) {
    constexpr int C = CIN + HH;
    constexpr int C2 = 2 * C;                     // 130 / 256
    constexpr int C2E = (CIN == 64) ? 256 : 132;  // padded to /4; pads zeroed
    constexpr int KC = (CIN == 64) ? 64 : 44;     // chunk ki-count (C2E % KC == 0)
    int n = blockIdx.x;
    __shared__ float xg[32][C2E];
    __shared__ float Wl[KC][128];
    for (int idx = threadIdx.x; idx < 32 * C2E; idx += 256) {
        int bl = idx / C2E, ki = idx - bl * C2E;
        float v = 0.f;
        if (ki < C2) {
            if constexpr (CIN == 64) {
                int seg = ki >> 6, c = ki & 63;
                if (seg == 0)      v = g_buf[OFF_OUT0 + (((size_t)t * NN + n) * 32 + bl) * 64 + c];
                else if (seg == 1) v = g_buf[OFF_H   + ((size_t)n * 32 + bl) * 64 + c];
                else if (seg == 2) v = g_buf[OFF_AX1 + (((size_t)t * NN + n) * 32 + bl) * 64 + c];
                else               v = g_buf[OFF_AGG + ((size_t)n * 32 + bl) * 64 + c];
            } else {
                if (ki == 0)       v = g_buf[S_SRC + ((size_t)bl * TT + t) * NN + n];
                else if (ki < 65)  v = g_buf[OFF_H + ((size_t)n * 32 + bl) * 64 + (ki - 1)];
                else if (ki == 65) v = g_buf[OFF_AX0 + ((size_t)t * NN + n) * 32 + bl];
                else               v = g_buf[OFF_AGG + ((size_t)n * 32 + bl) * 64 + (ki - 66)];
            }
        }
        xg[bl][ki] = v;
    }
    int o = threadIdx.x & 63;
    int bl0 = (threadIdx.x >> 6) * 8;
    const float* W  = g_buf + OFF_WB + (CIN == 64 ? WG1B : WG0B) + (size_t)n * (C2 * 128);
    const float* Bb = g_buf + OFF_WB + (CIN == 64 ? BG1B : BG0B) + (size_t)n * 128;
    float bz = Bb[o], br = Bb[o + 64];
    float accz[8], accr[8];
    #pragma unroll
    for (int j = 0; j < 8; j++) { accz[j] = bz; accr[j] = br; }
    for (int kc = 0; kc < C2E; kc += KC) {
        __syncthreads();
        // stage W chunk (linear float4 copy; overrun past C2 rows hits finite data x zero xg)
        const float4* wsrc = (const float4*)(W + (size_t)kc * 128);
        float4* wdst = (float4*)&Wl[0][0];
        for (int idx = threadIdx.x; idx < KC * 32; idx += 256) wdst[idx] = wsrc[idx];
        __syncthreads();
        #pragma unroll 4
        for (int kq = 0; kq < KC; kq += 4) {
            float4 xv[8];
            #pragma unroll
            for (int j = 0; j < 8; j++) xv[j] = *(const float4*)&xg[bl0 + j][kc + kq];
            #pragma unroll
            for (int q = 0; q < 4; q++) {
                float w0 = Wl[kq + q][o];
                float w1 = Wl[kq + q][o + 64];
                #pragma unroll
                for (int j = 0; j < 8; j++) {
                    float xx = ((const float*)&xv[j])[q];
                    accz[j] += xx * w0;
                    accr[j] += xx * w1;
                }
            }
        }
    }
    #pragma unroll
    for (int j = 0; j < 8; j++) {
        int b = bl0 + j;
        float z = 1.f / (1.f + expf(-accz[j]));
        float r = 1.f / (1.f + expf(-accr[j]));
        float hv = xg[b][(CIN == 64 ? 64 : 1) + o];
        size_t base = ((size_t)n * 32 + b) * 64 + o;
        g_buf[OFF_ZH + base] = z * hv;
        g_buf[OFF_R + base]  = r;
    }
}

// ---------------- update: hc = tanh(per-node GEMM); h = r*h + (1-r)*hc ----------------
template<int CIN, bool WOUT>
__global__ __launch_bounds__(256) void k_upd(int t) {
    constexpr int C = CIN + HH;
    constexpr int C2 = 2 * C;
    constexpr int C2E = (CIN == 64) ? 256 : 132;
    constexpr int KC = (CIN == 64) ? 64 : 44;
    int n = blockIdx.x;
    __shared__ float xg[32][C2E];
    __shared__ float Wl[KC][64];
    for (int idx = threadIdx.x; idx < 32 * C2E; idx += 256) {
        int bl = idx / C2E, ki = idx - bl * C2E;
        float v = 0.f;
        if (ki < C2) {
            if constexpr (CIN == 64) {
                int seg = ki >> 6, c = ki & 63;
                if (seg == 0)      v = g_buf[OFF_OUT0 + (((size_t)t * NN + n) * 32 + bl) * 64 + c];
                else if (seg == 1) v = g_buf[OFF_ZH  + ((size_t)n * 32 + bl) * 64 + c];
                else if (seg == 2) v = g_buf[OFF_AX1 + (((size_t)t * NN + n) * 32 + bl) * 64 + c];
                else               v = g_buf[OFF_AGG + ((size_t)n * 32 + bl) * 64 + c];
            } else {
                if (ki == 0)       v = g_buf[S_SRC + ((size_t)bl * TT + t) * NN + n];
                else if (ki < 65)  v = g_buf[OFF_ZH + ((size_t)n * 32 + bl) * 64 + (ki - 1)];
                else if (ki == 65) v = g_buf[OFF_AX0 + ((size_t)t * NN + n) * 32 + bl];
                else               v = g_buf[OFF_AGG + ((size_t)n * 32 + bl) * 64 + (ki - 66)];
            }
        }
        xg[bl][ki] = v;
    }
    int o = threadIdx.x & 63;
    int bl0 = (threadIdx.x >> 6) * 8;
    const float* W  = g_buf + OFF_WB + (CIN == 64 ? WU1B : WU0B) + (size_t)n * (C2 * 64);
    const float* Bb = g_buf + OFF_WB + (CIN == 64 ? BU1B : BU0B) + (size_t)n * 64;
    float bu = Bb[o];
    float acc[8];
    #pragma unroll
    for (int j = 0; j < 8; j++) acc[j] = bu;
    for (int kc = 0; kc < C2E; kc += KC) {
        __syncthreads();
        const float4* wsrc = (const float4*)(W + (size_t)kc * 64);
        float4* wdst = (float4*)&Wl[0][0];
        for (int idx = threadIdx.x; idx < KC * 16; idx += 256) wdst[idx] = wsrc[idx];
        __syncthreads();
        #pragma unroll 4
        for (int kq = 0; kq < KC; kq += 4) {
            float4 xv[8];
            #pragma unroll
            for (int j = 0; j < 8; j++) xv[j] = *(const float4*)&xg[bl0 + j][kc + kq];
            #pragma unroll
            for (int q = 0; q < 4; q++) {
                float w = Wl[kq + q][o];
                #pragma unroll
                for (int j = 0; j < 8; j++) acc[j] += ((const float*)&xv[j])[q] * w;
            }
        }
    }
    #pragma unroll
    for (int j = 0; j < 8; j++) {
        int b = bl0 + j;
        size_t base = ((size_t)n * 32 + b) * 64 + o;
        float hc = tanhf(acc[j]);
        float r = g_buf[OFF_R + base];
        float hold = g_buf[OFF_H + base];
        float hn = r * hold + (1.f - r) * hc;
        g_buf[OFF_H + base] = hn;
        if constexpr (WOUT)
            g_buf[OFF_OUT0 + (((size_t)t * NN + n) * 32 + b) * 64 + o] = hn;
    }
}

// ---------------- fused attention (t=T-1 only) + LN1; 4 (b,n) per block ----------------
__global__ __launch_bounds__(256) void k_attn() {
    int wid = threadIdx.x >> 6;
    int lane = threadIdx.x & 63;
    int g = blockIdx.x * 4 + wid;     // 0..9823
    int b = g / NN, n = g - b * NN;
    __shared__ float x[4][TT][HH], kk[4][TT][HH], vv[4][TT][HH];
    __shared__ float q[4][HH], o1[4][HH], sc[4][HEADS][TT], aw[4][HEADS][TT];
    float mw = g_buf[S_MLW + lane];
    float mb = g_buf[S_MLB + lane];
    #pragma unroll
    for (int tt = 0; tt < TT; tt++) {
        float s = g_buf[S_SRC + ((size_t)b * TT + tt) * NN + n];
        x[wid][tt][lane] = s * mw + mb + g_buf[OFF_PE + tt * HH + lane];
    }
    __syncthreads();
    float ka[TT], va[TT];
    #pragma unroll
    for (int tt = 0; tt < TT; tt++) { ka[tt] = g_buf[S_BK + lane]; va[tt] = g_buf[S_BV + lane]; }
    float qa = g_buf[S_BQ + lane];
    for (int i = 0; i < HH; i++) {
        float wkv = g_buf[S_WK + i * HH + lane];
        float wvv = g_buf[S_WV + i * HH + lane];
        qa += x[wid][TT - 1][i] * g_buf[S_WQ + i * HH + lane];
        #pragma unroll
        for (int tt = 0; tt < TT; tt++) {
            float xv = x[wid][tt][i];
            ka[tt] += xv * wkv;
            va[tt] += xv * wvv;
        }
    }
    #pragma unroll
    for (int tt = 0; tt < TT; tt++) { kk[wid][tt][lane] = ka[tt]; vv[wid][tt][lane] = va[tt]; }
    q[wid][lane] = qa;
    __syncthreads();
    if (lane < HEADS * TT) {
        int head = lane / TT, ts = lane - head * TT;
        float s = 0.f;
        #pragma unroll
        for (int d = 0; d < HD; d++) s += q[wid][head * HD + d] * kk[wid][ts][head * HD + d];
        sc[wid][head][ts] = s * 0.25f;
    }
    __syncthreads();
    if (lane < HEADS * TT) {
        int head = lane / TT, ts = lane - head * TT;
        float mx = -1e30f;
        #pragma unroll
        for (int j = 0; j < TT; j++) mx = fmaxf(mx, sc[wid][head][j]);
        float sm = 0.f;
        #pragma unroll
        for (int j = 0; j < TT; j++) sm += expf(sc[wid][head][j] - mx);
        aw[wid][head][ts] = expf(sc[wid][head][ts] - mx) / sm;
    }
    __syncthreads();
    int head = lane >> 4;
    float oa = 0.f;
    #pragma unroll
    for (int tt = 0; tt < TT; tt++) oa += aw[wid][head][tt] * vv[wid][tt][lane];
    o1[wid][lane] = oa;
    __syncthreads();
    float acc = g_buf[S_BO + lane];
    for (int i = 0; i < HH; i++) acc += o1[wid][i] * g_buf[S_WO + i * HH + lane];
    float res = x[wid][TT - 1][lane] + acc;
    float mean = wave_sum(res) * (1.f / 64.f);
    float dv = res - mean;
    float var = wave_sum(dv * dv) * (1.f / 64.f);
    float ln = dv * rsqrtf(var + 1e-5f) * g_buf[S_L1G + lane] + g_buf[S_L1B + lane];
    g_buf[OFF_OLN + ((size_t)b * NN + n) * HH + lane] = ln;
}

// ---------------- FFN + LN2; 8 tokens per block ----------------
__global__ __launch_bounds__(256) void k_ffn() {
    int tok0 = blockIdx.x * 8;        // 9824 = 1228 * 8
    int tid = threadIdx.x;
    __shared__ float ox[8][HH];
    __shared__ float hid[8][1024];
    for (int idx = tid; idx < 8 * HH; idx += 256) {
        int tk = idx >> 6, hh = idx & 63;
        ox[tk][hh] = g_buf[OFF_OLN + (size_t)(tok0 + tk) * HH + hh];
    }
    __syncthreads();
    #pragma unroll
    for (int p = 0; p < 4; p++) {
        int j = tid + 256 * p;
        float bj = g_buf[S_FB1 + j];
        float a[8];
        #pragma unroll
        for (int tk = 0; tk < 8; tk++) a[tk] = bj;
        for (int i = 0; i < HH; i++) {
            float w = g_buf[S_FW1 + (size_t)i * 1024 + j];
            #pragma unroll
            for (int tk = 0; tk < 8; tk++) a[tk] += ox[tk][i] * w;
        }
        #pragma unroll
        for (int tk = 0; tk < 8; tk++) hid[tk][j] = fmaxf(a[tk], 0.f);
    }
    __syncthreads();
    int tk = tid >> 6, hh = tid & 63; // tokens tk and tk+4 per thread
    float acc0 = g_buf[S_FB2 + hh], acc1 = acc0;
    for (int j = 0; j < 1024; j++) {
        float w = g_buf[S_FW2 + (size_t)j * HH + hh];
        acc0 += hid[tk][j] * w;
        acc1 += hid[tk + 4][j] * w;
    }
    #pragma unroll
    for (int ph = 0; ph < 2; ph++) {
        int tkk = tk + 4 * ph;
        float res = ox[tkk][hh] + (ph ? acc1 : acc0);
        float mean = wave_sum(res) * (1.f / 64.f);
        float dv = res - mean;
        float var = wave_sum(dv * dv) * (1.f / 64.f);
        float ln = dv * rsqrtf(var + 1e-5f) * g_buf[S_L2G + hh] + g_buf[S_L2B + hh];
        g_buf[OFF_O2 + (size_t)(tok0 + tkk) * HH + hh] = ln;
    }
}

// ---------------- final combine + horizon conv ----------------
__global__ void k_final(void* out) {
    int n = blockIdx.x, b = blockIdx.y;
    int h = threadIdx.x;              // 64
    __shared__ float comb[HH];
    comb[h] = g_buf[OFF_H + ((size_t)n * 32 + b) * 64 + h] * g_buf[S_WS + n * HH + h]
            + g_buf[OFF_O2 + ((size_t)b * NN + n) * 64 + h] * g_buf[S_WT + n * HH + h];
    __syncthreads();
    if (h < HORIZON) {
        float acc = g_buf[S_CB + h];
        #pragma unroll
        for (int i = 0; i < HH; i++) acc += comb[i] * g_buf[S_CW + h * HH + i];
        size_t oi = ((size_t)b * HORIZON + h) * NN + n;
        if (g_flag) ((bf16*)out)[oi] = __float2bfloat16(acc);
        else        ((float*)out)[oi] = acc;
    }
}

extern "C" void kernel_launch(void* const* d_in, const int* in_sizes, int n_in,
                              void* d_out, int out_size, void* d_ws, size_t ws_size,
                              hipStream_t stream) {
    PtrPack pk;
    for (int i = 0; i < 32; i++) pk.p[i] = d_in[i];

    k_detect<<<1, 64, 0, stream>>>(d_in[1]);
    k_ingest<<<4133, 256, 0, stream>>>(pk);
    k_adj<<<NN, 512, 0, stream>>>();
    k_nodew_all<<<89337, 256, 0, stream>>>();
    k_pe<<<1, 768, 0, stream>>>();
    k_ax0<<<dim3(39, 12), 256, 0, stream>>>();   // 39*8 = 312 >= 307

    // ---- GRU layer 0 (C_in = 1) ----
    k_zero<<<2456, 256, 0, stream>>>(OFF_H, 628736);
    for (int t = 0; t < TT; t++) {
        k_aggmat<<<dim3(5, 32, 1), 256, 0, stream>>>(OFF_H, OFF_AGG, 0, 0);
        k_gate<1><<<NN, 256, 0, stream>>>(t);
        k_aggmat<<<dim3(5, 32, 1), 256, 0, stream>>>(OFF_ZH, OFF_AGG, 0, 0);
        k_upd<1, true><<<NN, 256, 0, stream>>>(t);
    }
    // ---- AX1[t] = A @ out0[t] for all t (parallel) ----
    k_aggmat<<<dim3(5, 32, 12), 256, 0, stream>>>(OFF_OUT0, OFF_AX1, 628736, 628736);
    // ---- GRU layer 1 (C_in = 64) ----
    k_zero<<<2456, 256, 0, stream>>>(OFF_H, 628736);
    for (int t = 0; t < TT; t++) {
        k_aggmat<<<dim3(5, 32, 1), 256, 0, stream>>>(OFF_H, OFF_AGG, 0, 0);
        k_gate<64><<<NN, 256, 0, stream>>>(t);
        k_aggmat<<<dim3(5, 32, 1), 256, 0, stream>>>(OFF_ZH, OFF_AGG, 0, 0);
        k_upd<64, false><<<NN, 256, 0, stream>>>(t);
    }
    // ---- transformer branch ----
    k_attn<<<2456, 256, 0, stream>>>();
    k_ffn<<<1228, 256, 0, stream>>>();
    // ---- combine + conv ----
    k_final<<<dim3(NN, BB), 64, 0, stream>>>(d_out);
}